// Round 1
// baseline (12423.415 us; speedup 1.0000x reference)
//
#include <hip/hip_runtime.h>
#include <math.h>

// MPGRUImputer on MI355X. B=8, F=1, N=1024, T=128, H=64, ORDER=2.
// Per step: diffusion = Z[528x1024] x {A_f, A_f^2, A_b, A_b^2}^T (bf16 MFMA),
// 1x1 convs (bf16 MFMA, K=416: [xh_hi(66) | xh_lo(66) | z(264) | pad(20)]),
// pointwise fused into conv epilogues. 4 kernels/step + 5 setup kernels.

typedef unsigned short u16;
typedef unsigned int u32;
typedef short bf16x8 __attribute__((ext_vector_type(8)));  // 8 bf16 = 4 VGPRs
typedef float f32x4 __attribute__((ext_vector_type(4)));

#define MFMA16(a, b, c) __builtin_amdgcn_mfma_f32_16x16x32_bf16((a), (b), (c), 0, 0, 0)

#define Bz 8
#define Nn 1024
#define Tt 128
#define Hh 64
#define KC 416   // padded conv K: 66 hi + 66 lo + 4*66 z + 20 zero
#define CP 80    // padded diffusion M rows per batch (66 valid)

static __device__ __forceinline__ u16 f2b(float f) {  // RNE f32->bf16
  u32 u = __float_as_uint(f);
  u = (u + 0x7FFFu + ((u >> 16) & 1u)) >> 16;
  return (u16)u;
}
static __device__ __forceinline__ float b2f(u16 s) { return __uint_as_float(((u32)s) << 16); }
static __device__ __forceinline__ bf16x8 ld8(const u16* p) { return *reinterpret_cast<const bf16x8*>(p); }
static __device__ __forceinline__ void st2f(u16* p, float a, float b) {
  *reinterpret_cast<u32*>(p) = (u32)f2b(a) | ((u32)f2b(b) << 16);
}
static __device__ __forceinline__ void st2u(u16* p, u16 a, u16 b) {
  *reinterpret_cast<u32*>(p) = (u32)a | ((u32)b << 16);
}
static __device__ __forceinline__ float sigm(float x) { return 1.f / (1.f + __expf(-x)); }
static __device__ __forceinline__ float tanh_f(float x) {
  x = fminf(fmaxf(x, -15.f), 15.f);
  float e = __expf(2.f * x);
  return (e - 1.f) / (e + 1.f);
}

// ---- setup: row/col sums of adj -> 1/(sum+eps) ------------------------------
__global__ __launch_bounds__(256) void ksums(const float* adj, float* rinv, float* cinv) {
  int id = blockIdx.x * 256 + threadIdx.x;  // 0..2047
  if (id < 1024) {
    int w = id;  // column sum (coalesced across threads)
    float s = 0.f;
    for (int v = 0; v < 1024; ++v) s += adj[v * 1024 + w];
    cinv[w] = 1.f / (s + 1e-8f);
  } else {
    int w = id - 1024;  // row sum
    float s = 0.f;
    for (int v = 0; v < 1024; ++v) s += adj[w * 1024 + v];
    rinv[w] = 1.f / (s + 1e-8f);
  }
}

// ---- setup: build bf16 operators A_f, A_b (+ transposed copies for A^2 GEMM)
// Aops layout: [op][w][v], op: 0=A_f, 1=A_f^2, 2=A_b, 3=A_b^2
__global__ __launch_bounds__(256) void kmakeops(const float* adj, const float* rinv, const float* cinv,
                                                u16* Aops, u16* supft, u16* supbt) {
  int idx = blockIdx.x * 256 + threadIdx.x;  // w*1024+v, v coalesced
  int w = idx >> 10, v = idx & 1023;
  float a = adj[idx];
  u16 f = f2b(a * rinv[w]);   // A_f[w][v]
  u16 bb = f2b(a * cinv[v]);  // = A_b[v][w]
  Aops[idx] = f;
  supft[v * 1024 + w] = f;              // A_f^T[v][w]
  supbt[idx] = bb;                      // A_b^T[w][v]
  Aops[2 * 1048576 + v * 1024 + w] = bb;  // A_b[v][w]
}

// ---- setup: A^2 via bf16 MFMA: out[w][v] = sum_u A[w][u]*A[u][v] ------------
__global__ __launch_bounds__(256) void kA2(u16* Aops, const u16* supft, const u16* supbt) {
  int wg = blockIdx.x;  // 2 * 8 * 8 = 128
  int o2 = wg & 1, mt = (wg >> 1) & 7, ntt = (wg >> 4) & 7;
  const u16* Ab = Aops + (o2 ? 2 * 1048576 : 0);
  const u16* Bb = o2 ? supbt : supft;
  u16* Ob = Aops + (o2 ? 3 * 1048576 : 1048576);
  int tid = threadIdx.x, wave = tid >> 6, lane = tid & 63, l15 = lane & 15, quad = lane >> 4;
  int mbase = mt * 128 + wave * 32;
  f32x4 acc[2][8];
#pragma unroll
  for (int m = 0; m < 2; ++m)
#pragma unroll
    for (int j = 0; j < 8; ++j) acc[m][j] = (f32x4){0.f, 0.f, 0.f, 0.f};
  for (int k = 0; k < 1024; k += 32) {
    int kq = k + quad * 8;
    bf16x8 av[2], bv[8];
#pragma unroll
    for (int m = 0; m < 2; ++m) av[m] = ld8(Ab + (mbase + m * 16 + l15) * 1024 + kq);
#pragma unroll
    for (int j = 0; j < 8; ++j) bv[j] = ld8(Bb + (ntt * 128 + j * 16 + l15) * 1024 + kq);
#pragma unroll
    for (int m = 0; m < 2; ++m)
#pragma unroll
      for (int j = 0; j < 8; ++j) acc[m][j] = MFMA16(av[m], bv[j], acc[m][j]);
  }
#pragma unroll
  for (int m = 0; m < 2; ++m)
#pragma unroll
    for (int j = 0; j < 8; ++j) {
      int v = ntt * 128 + j * 16 + l15;
#pragma unroll
      for (int i = 0; i < 4; ++i) {
        int w = mbase + m * 16 + quad * 4 + i;
        Ob[w * 1024 + v] = f2b(acc[m][j][i]);
      }
    }
}

// ---- setup: pack weights to bf16, K=416 layout ------------------------------
__global__ __launch_bounds__(256) void kpackw(const float* Wr, const float* Wu, const float* Wc,
                                              u16* Wrup, u16* Wcp) {
  int idx = blockIdx.x * 256 + threadIdx.x;  // 192*416 = 79872
  int r = idx / KC, k = idx % KC;
  float wv = 0.f;
  if (k < 396) {
    int c = (k < 66) ? k : (k - 66);  // hi block: c=k; lo block + diffused: c=k-66
    if (r < 64) wv = Wr[r * 330 + c];
    else if (r < 128) wv = Wu[(r - 64) * 330 + c];
    else wv = Wc[(r - 128) * 330 + c];
  }
  if (r < 128) Wrup[r * KC + k] = f2b(wv);
  else Wcp[(r - 128) * KC + k] = f2b(wv);
}

// ---- setup: t=0 state, outputs, staging buffers, zero pads ------------------
__global__ __launch_bounds__(256) void kstep0(const float* x, const int* mask, const float* bout,
                                              float* h, float* states, float* preds,
                                              u16* xh, u16* xc, u16* zct, u16* yct) {
  int idx = blockIdx.x * 256 + threadIdx.x;  // b*65536 + o*1024 + n
  int b = idx >> 16, o = (idx >> 10) & 63, n = idx & 1023;
  int hidx = (b * 64 + o) * 1024 + n;
  h[hidx] = 0.f;
  states[hidx * 128] = 0.f;  // states[t=0] = h0 = 0
  xh[(b * CP + 2 + o) * 1024 + n] = 0;
  zct[(b * 1024 + n) * KC + 2 + o] = 0;
  zct[(b * 1024 + n) * KC + 68 + o] = 0;
  if (o == 0) {
    int xi = (b * 1024 + n) * 128;
    float xhat = bout[0];  // Wout . 0 + bout
    int mv = mask[xi];
    float xin = mv ? x[xi] : xhat;
    preds[xi] = xhat;
    u16 hi = f2b(xin), lo = f2b(xin - b2f(hi));
    xh[(b * CP + 0) * 1024 + n] = hi;
    xh[(b * CP + 1) * 1024 + n] = f2b((float)mv);
    u16* zr = zct + (b * 1024 + n) * KC;
    zr[0] = hi; zr[1] = f2b((float)mv); zr[66] = lo; zr[67] = 0;
  } else if (o == 1) {
    for (int j = 66; j < 80; ++j) {
      xh[(b * CP + j) * 1024 + n] = 0;
      xc[(b * CP + j) * 1024 + n] = 0;
    }
    u16* zr = zct + (b * 1024 + n) * KC;
    u16* yr = yct + (b * 1024 + n) * KC;
    for (int j = 396; j < KC; ++j) { zr[j] = 0; yr[j] = 0; }
  }
}

// ---- per-step: diffusion z_op = Z x Aops[op]^T, write bf16 into [n][c] ------
// grid 256: bits [b:3][ntl:2][op:2][nth:1] so blockIdx%8 pins (op,n-half) per XCD
__global__ __launch_bounds__(256) void kdiff(const u16* __restrict__ Zin, const u16* __restrict__ Aops,
                                             u16* __restrict__ outT) {
  int wg = blockIdx.x;
  int nth = wg & 1, op = (wg >> 1) & 3, ntl = (wg >> 3) & 3, b = (wg >> 5) & 7;
  int nt = nth * 4 + ntl;
  int tid = threadIdx.x, wave = tid >> 6, lane = tid & 63, l15 = lane & 15, quad = lane >> 4;
  const u16* Zb = Zin + b * CP * 1024;
  const u16* Ab = Aops + op * 1048576;
  int colbase = nt * 128 + wave * 32;
  f32x4 acc[5][2];
#pragma unroll
  for (int m = 0; m < 5; ++m)
#pragma unroll
    for (int j = 0; j < 2; ++j) acc[m][j] = (f32x4){0.f, 0.f, 0.f, 0.f};
  for (int k = 0; k < 1024; k += 32) {
    int kq = k + quad * 8;
    bf16x8 av[5], bv[2];
#pragma unroll
    for (int m = 0; m < 5; ++m) av[m] = ld8(Zb + (m * 16 + l15) * 1024 + kq);
#pragma unroll
    for (int j = 0; j < 2; ++j) bv[j] = ld8(Ab + (colbase + j * 16 + l15) * 1024 + kq);
#pragma unroll
    for (int m = 0; m < 5; ++m)
#pragma unroll
      for (int j = 0; j < 2; ++j) acc[m][j] = MFMA16(av[m], bv[j], acc[m][j]);
  }
  int cbase = 132 + op * 66;
#pragma unroll
  for (int j = 0; j < 2; ++j) {
    int w = colbase + j * 16 + l15;
    u16* orow = outT + (b * 1024 + w) * KC + cbase;
#pragma unroll
    for (int m = 0; m < 5; ++m) {
      int c0 = m * 16 + quad * 4;
      if (c0 < 64) {
        st2f(orow + c0, acc[m][j][0], acc[m][j][1]);
        st2f(orow + c0 + 2, acc[m][j][2], acc[m][j][3]);
      } else if (c0 == 64) {  // m==4, quad==0: channels 64,65 only
        st2f(orow + 64, acc[m][j][0], acc[m][j][1]);
      }
    }
  }
}

// ---- per-step: r,u gates; write u, build xc = [x_in, mask, r*h] -------------
__global__ __launch_bounds__(256) void kconv_ru(const u16* __restrict__ zct, const u16* __restrict__ Wrup,
                                                const float* br, const float* bu,
                                                const float* __restrict__ h, float* __restrict__ ubuf,
                                                u16* __restrict__ xc, u16* __restrict__ yct) {
  int wg = blockIdx.x;  // 8b * 32nt
  int b = wg >> 5, nt = wg & 31;
  int tid = threadIdx.x, wave = tid >> 6, lane = tid & 63, l15 = lane & 15, quad = lane >> 4;
  int obase = wave * 32;
  f32x4 acc[2][2];
#pragma unroll
  for (int m = 0; m < 2; ++m)
#pragma unroll
    for (int j = 0; j < 2; ++j) acc[m][j] = (f32x4){0.f, 0.f, 0.f, 0.f};
  for (int k = 0; k < KC; k += 32) {
    int kq = k + quad * 8;
    bf16x8 av[2], bv[2];
#pragma unroll
    for (int m = 0; m < 2; ++m) av[m] = ld8(Wrup + (obase + m * 16 + l15) * KC + kq);
#pragma unroll
    for (int j = 0; j < 2; ++j) bv[j] = ld8(zct + ((b * 1024 + nt * 32 + j * 16 + l15) * KC + kq));
#pragma unroll
    for (int m = 0; m < 2; ++m)
#pragma unroll
      for (int j = 0; j < 2; ++j) acc[m][j] = MFMA16(av[m], bv[j], acc[m][j]);
  }
#pragma unroll
  for (int m = 0; m < 2; ++m)
#pragma unroll
    for (int j = 0; j < 2; ++j) {
      int o0 = obase + m * 16 + quad * 4;
      int n = nt * 32 + j * 16 + l15;
      if (o0 < 64) {  // r gate -> r*h into xc (diff A-op) and yct hi/lo (conv B-op)
        u16 hi[4], lo[4];
#pragma unroll
        for (int i = 0; i < 4; ++i) {
          float s = sigm(acc[m][j][i] + br[o0 + i]);
          float rh = s * h[(b * 64 + o0 + i) * 1024 + n];
          hi[i] = f2b(rh);
          lo[i] = f2b(rh - b2f(hi[i]));
          xc[(b * CP + 2 + o0 + i) * 1024 + n] = hi[i];
        }
        u16* yr = yct + (b * 1024 + n) * KC;
        st2u(yr + 2 + o0, hi[0], hi[1]);
        st2u(yr + 4 + o0, hi[2], hi[3]);
        st2u(yr + 68 + o0, lo[0], lo[1]);
        st2u(yr + 70 + o0, lo[2], lo[3]);
      } else {  // u gate
#pragma unroll
        for (int i = 0; i < 4; ++i)
          ubuf[(b * 64 + o0 - 64 + i) * 1024 + n] = sigm(acc[m][j][i] + bu[o0 - 64 + i]);
      }
    }
  if (tid < 32) {  // copy x_in/mask channels into phase-B buffers
    int n = nt * 32 + tid;
    const u16* zr = zct + (b * 1024 + n) * KC;
    u16* yr = yct + (b * 1024 + n) * KC;
    yr[0] = zr[0]; yr[1] = zr[1]; yr[66] = zr[66]; yr[67] = zr[67];
    xc[(b * CP + 0) * 1024 + n] = zr[0];
    xc[(b * CP + 1) * 1024 + n] = zr[1];
  }
}

// ---- per-step: c gate, h update, x_hat/preds/states, stage next-step xh -----
__global__ __launch_bounds__(256) void kconv_c(const u16* __restrict__ yct, const u16* __restrict__ Wcp,
                                               const float* bc, const float* __restrict__ ubuf,
                                               float* __restrict__ h, const float* __restrict__ x,
                                               const int* __restrict__ mask, const float* Wout,
                                               const float* bout, float* __restrict__ preds,
                                               float* __restrict__ states, u16* __restrict__ xh,
                                               u16* __restrict__ zct, int t) {
  __shared__ float lds[64 * 65];
  int wg = blockIdx.x;  // 8b * 16nt
  int b = wg >> 4, nt = wg & 15;
  int tid = threadIdx.x, wave = tid >> 6, lane = tid & 63, l15 = lane & 15, quad = lane >> 4;
  int nl = wave * 16 + l15;
  int n = nt * 64 + nl;
  f32x4 acc[4];
#pragma unroll
  for (int m = 0; m < 4; ++m) acc[m] = (f32x4){0.f, 0.f, 0.f, 0.f};
  for (int k = 0; k < KC; k += 32) {
    int kq = k + quad * 8;
    bf16x8 bv = ld8(yct + (b * 1024 + n) * KC + kq);
#pragma unroll
    for (int m = 0; m < 4; ++m) {
      bf16x8 av = ld8(Wcp + (m * 16 + l15) * KC + kq);
      acc[m] = MFMA16(av, bv, acc[m]);
    }
  }
  int t1 = t + 1;
#pragma unroll
  for (int m = 0; m < 4; ++m) {
    int o0 = m * 16 + quad * 4;
    u16 hi[4], lo[4];
#pragma unroll
    for (int i = 0; i < 4; ++i) {
      int o = o0 + i;
      float c = tanh_f(acc[m][i] + bc[o]);
      int idx = (b * 64 + o) * 1024 + n;
      float u = ubuf[idx], hp = h[idx];
      float hn = u * hp + (1.f - u) * c;
      h[idx] = hn;
      lds[o * 65 + nl] = hn;
      hi[i] = f2b(hn);
      lo[i] = f2b(hn - b2f(hi[i]));
      if (t1 < Tt) {
        states[idx * 128 + t1] = hn;
        xh[(b * CP + 2 + o) * 1024 + n] = hi[i];
      }
    }
    if (t1 < Tt) {
      u16* zr = zct + (b * 1024 + n) * KC;
      st2u(zr + 2 + o0, hi[0], hi[1]);
      st2u(zr + 4 + o0, hi[2], hi[3]);
      st2u(zr + 68 + o0, lo[0], lo[1]);
      st2u(zr + 70 + o0, lo[2], lo[3]);
    }
  }
  __syncthreads();
  if (tid < 64 && t1 < Tt) {
    int nn = nt * 64 + tid;
    float xhat = bout[0];
    for (int o = 0; o < 64; ++o) xhat += Wout[o] * lds[o * 65 + tid];
    int xi = (b * 1024 + nn) * 128 + t1;
    int mv = mask[xi];
    float xin = mv ? x[xi] : xhat;
    preds[xi] = xhat;
    u16 hi = f2b(xin), lo = f2b(xin - b2f(hi));
    xh[(b * CP + 0) * 1024 + nn] = hi;
    xh[(b * CP + 1) * 1024 + nn] = f2b((float)mv);
    u16* zr = zct + (b * 1024 + nn) * KC;
    zr[0] = hi; zr[1] = f2b((float)mv); zr[66] = lo; zr[67] = 0;
  }
}

extern "C" void kernel_launch(void* const* d_in, const int* in_sizes, int n_in,
                              void* d_out, int out_size, void* d_ws, size_t ws_size,
                              hipStream_t stream) {
  const float* x = (const float*)d_in[0];
  const int* mask = (const int*)d_in[1];
  const float* adj = (const float*)d_in[2];
  const float* Wr = (const float*)d_in[3];
  const float* br = (const float*)d_in[4];
  const float* Wu = (const float*)d_in[5];
  const float* bu = (const float*)d_in[6];
  const float* Wc = (const float*)d_in[7];
  const float* bc = (const float*)d_in[8];
  const float* Wout = (const float*)d_in[9];
  const float* bout = (const float*)d_in[10];

  float* preds = (float*)d_out;                  // [8,1,1024,128]
  float* states = preds + 8 * 1024 * 128;        // [1,8,64,1024,128]

  // workspace carve-up (bf16 buffers as u16; all MFMA-load bases 16B aligned)
  u16* Aops = (u16*)d_ws;                        // [4][1024][1024]
  u16* supft = Aops + 4 * 1048576;               // A_f^T
  u16* supbt = supft + 1048576;                  // A_b^T
  float* rinv = (float*)(supbt + 1048576);
  float* cinv = rinv + 1024;
  u16* xh = (u16*)(cinv + 1024);                 // [8][80][1024] diffusion A-op, phase A
  u16* xc = xh + Bz * CP * 1024;                 // [8][80][1024] phase B
  u16* zct = xc + Bz * CP * 1024;                // [8][1024][416] conv B-op, phase A
  u16* yct = zct + Bz * 1024 * KC;               // [8][1024][416] phase B
  u16* Wrup = yct + Bz * 1024 * KC;              // [128][416]
  u16* Wcp = Wrup + 128 * KC;                    // [64][416]
  float* ubuf = (float*)(Wcp + 64 * KC);         // [8][64][1024]
  float* h = ubuf + Bz * 64 * 1024;              // [8][64][1024]

  ksums<<<8, 256, 0, stream>>>(adj, rinv, cinv);
  kmakeops<<<4096, 256, 0, stream>>>(adj, rinv, cinv, Aops, supft, supbt);
  kA2<<<128, 256, 0, stream>>>(Aops, supft, supbt);
  kpackw<<<312, 256, 0, stream>>>(Wr, Wu, Wc, Wrup, Wcp);
  kstep0<<<2048, 256, 0, stream>>>(x, mask, bout, h, states, preds, xh, xc, zct, yct);

  for (int t = 0; t < Tt; ++t) {
    kdiff<<<256, 256, 0, stream>>>(xh, Aops, zct);
    kconv_ru<<<256, 256, 0, stream>>>(zct, Wrup, br, bu, h, ubuf, xc, yct);
    kdiff<<<256, 256, 0, stream>>>(xc, Aops, yct);
    kconv_c<<<128, 256, 0, stream>>>(yct, Wcp, bc, ubuf, h, x, mask, Wout, bout,
                                     preds, states, xh, zct, t);
  }
}